// Round 7
// baseline (304.995 us; speedup 1.0000x reference)
//
#include <hip/hip_runtime.h>

// expRNN/modReLU recurrence, B=8192, T=784, I=1, H=30, C=10.
//
// Round 7: R6's split-precision bf16 MFMA, de-bloated epilogue.
//   - Same verified layout identity: A-frags hold W rows interleaved
//     (A-row r holds W row 8*(r>>2)+(r&3)+4g) so the MFMA C-layout
//     (col=lane&15,row=quad*4+i) is EXACTLY the next step's B-layout
//     (n=lane&15,k=quad*8+j). Lane (m,q) owns h rows 8q..8q+7 of batch m.
//     Zero cross-lane exchange in the T loop.
//   - Changes vs R6 (each targets measured ~200 VALU/iter vs 83 counted):
//     1. pack8 via perm + __builtin_bit_cast (no union -> no scratch).
//     2. 2 six-deep acc chains (was 4x3-deep): kills 8 z-adds + 8 inits.
//     3. x enters as acc init c[i] = W_ih[row]*x_m (f32): kills the
//        augmented h[30] slot, its cndmask, and x's bf16-split path.
//     4. x prefetched 2 steps ahead -> lgkm wait off the critical path.
//   - Numerics: exact truncation splits h=h1+h2+h3, W=w1+w2+w3; 6 product
//     terms (11,21,31,12,22,13) -> per-step error ~2^-23. R6 measured
//     absmax 3.2e29 = threshold/6.2 with identical math; x-term now f32
//     (slightly better). Expect ~same absmax.

#define T_STEPS 784
#define NBATCH  8192
#define NH      30
#define NC      10
#define BPW     16    // batches per wave
#define XPAD    788   // padded x row; 20*m mod 32 -> max 2-way (free)

typedef short bf16x8 __attribute__((ext_vector_type(8)));
typedef float f32x4  __attribute__((ext_vector_type(4)));
typedef unsigned int u32x4 __attribute__((ext_vector_type(4)));

#define MFMA(acc, a, b) \
    acc = __builtin_amdgcn_mfma_f32_16x16x32_bf16(a, b, acc, 0, 0, 0)

__device__ __forceinline__ float truncbf(float x) {
    return __int_as_float(__float_as_int(x) & 0xFFFF0000);
}
// one dword = bf16(lo) | bf16(hi)<<16  (hi16 bit-slices via byte perm)
__device__ __forceinline__ unsigned pk2(float lo, float hi) {
    return __builtin_amdgcn_perm(__float_as_uint(hi), __float_as_uint(lo),
                                 0x07060302u);
}
__device__ __forceinline__ bf16x8 pk8(float a0, float a1, float a2, float a3,
                                      float a4, float a5, float a6, float a7) {
    u32x4 u = { pk2(a0, a1), pk2(a2, a3), pk2(a4, a5), pk2(a6, a7) };
    return __builtin_bit_cast(bf16x8, u);
}
__device__ __forceinline__ float modrelu(float z, float b) {
    return copysignf(fmaxf(fabsf(z) + b, 0.0f), z);
}

__global__ __launch_bounds__(64, 1)
void rnn_modrelu_mfma2(const float* __restrict__ inp,    // [B, T, 1]
                       const float* __restrict__ W_ih,   // [H, 1]
                       const float* __restrict__ W_hh,   // [H, H]
                       const float* __restrict__ b_mod,  // [H]
                       const float* __restrict__ W_lin,  // [C, H]
                       const float* __restrict__ b_lin,  // [C]
                       float* __restrict__ out)          // [B, C]
{
    __shared__ __align__(16) float xl[BPW * XPAD];   // 50.4 KB
    __shared__ float hf[BPW * 32];

    const int l   = threadIdx.x;
    const int blk = blockIdx.x;
    const int m   = l & 15;     // batch column (A row / B col / C col)
    const int q   = l >> 4;     // quad: owns h rows 8q..8q+7 after each step

    // ---- preload x: 16 batches x 784 floats, coalesced, padded rows ----
    {
        const float4* src = (const float4*)(inp + (size_t)blk * (BPW * T_STEPS));
        #pragma unroll
        for (int k = 0; k < 49; ++k) {
            int v = l + 64 * k;                 // < 3136 float4
            if (v < (BPW * T_STEPS) / 4) {
                int b   = v / 196;
                int rem = v - b * 196;
                *(float4*)(xl + b * XPAD + 4 * rem) = src[v];
            }
        }
    }

    // ---- A fragments: W rows interleaved, 3 split terms, 2 row-groups ----
    bf16x8 afr[2][3];
    #pragma unroll
    for (int g = 0; g < 2; ++g) {
        const int row = 8 * (m >> 2) + (m & 3) + 4 * g;   // W row at A-pos m
        float wv[8], r1v[8], r2v[8];
        #pragma unroll
        for (int j = 0; j < 8; ++j) {
            const int col = q * 8 + j;
            float v = (row < NH && col < NH) ? W_hh[row * NH + col] : 0.0f;
            wv[j]  = v;
            r1v[j] = v - truncbf(v);
            r2v[j] = r1v[j] - truncbf(r1v[j]);
        }
        afr[g][0] = pk8(wv[0],  wv[1],  wv[2],  wv[3],  wv[4],  wv[5],  wv[6],  wv[7]);
        afr[g][1] = pk8(r1v[0], r1v[1], r1v[2], r1v[3], r1v[4], r1v[5], r1v[6], r1v[7]);
        afr[g][2] = pk8(r2v[0], r2v[1], r2v[2], r2v[3], r2v[4], r2v[5], r2v[6], r2v[7]);
    }

    // per-lane row metadata: lane owns h rows 8q+i (i=0..7)
    float bm[8], wih[8];
    #pragma unroll
    for (int i = 0; i < 8; ++i) {
        const int row = 8 * q + i;
        bm[i]  = (row < NH) ? b_mod[row] : 0.0f;
        wih[i] = (row < NH) ? W_ih[row]  : 0.0f;
    }

    __syncthreads();

    const float* xb = xl + m * XPAD;   // this lane's batch x row
    float xcur = xb[0];
    float xnx  = (T_STEPS > 1) ? xb[1] : xb[0];

    bf16x8 bf1 = {0,0,0,0,0,0,0,0};
    bf16x8 bf2 = {0,0,0,0,0,0,0,0};
    bf16x8 bf3 = {0,0,0,0,0,0,0,0};
    float hv[8];
    #pragma unroll
    for (int i = 0; i < 8; ++i) hv[i] = 0.0f;

    // ---- recurrence ----
    #pragma unroll 1
    for (int t = 0; t < T_STEPS; ++t) {
        // prefetch x_{t+2}: wait lands a full iteration after issue
        int tf = t + 2; if (tf >= T_STEPS) tf = T_STEPS - 1;
        const float xf = xb[tf];

        // acc init carries the x term (f32, exact-ish): c rows = W rows 8q+i
        f32x4 c0, c1;
        #pragma unroll
        for (int i = 0; i < 4; ++i) {
            c0[i] = wih[i]     * xcur;
            c1[i] = wih[4 + i] * xcur;
        }

        // 6 precision terms per row-group; bf1-consumers first; two
        // independent same-acc chains (back-to-back accumulate is free)
        MFMA(c0, afr[0][0], bf1);  MFMA(c1, afr[1][0], bf1);   // w1*h1
        MFMA(c0, afr[0][1], bf1);  MFMA(c1, afr[1][1], bf1);   // w2*h1
        MFMA(c0, afr[0][2], bf1);  MFMA(c1, afr[1][2], bf1);   // w3*h1
        MFMA(c0, afr[0][0], bf2);  MFMA(c1, afr[1][0], bf2);   // w1*h2
        MFMA(c0, afr[0][1], bf2);  MFMA(c1, afr[1][1], bf2);   // w2*h2
        MFMA(c0, afr[0][0], bf3);  MFMA(c1, afr[1][0], bf3);   // w1*h3

        // modReLU (pad rows: w==0, b==0, wih==0 -> stay exactly 0)
        #pragma unroll
        for (int i = 0; i < 4; ++i) {
            hv[i]     = modrelu(c0[i], bm[i]);
            hv[4 + i] = modrelu(c1[i], bm[4 + i]);
        }

        // exact 3-term truncation split -> next B fragments
        float r1[8], r2[8];
        #pragma unroll
        for (int j = 0; j < 8; ++j) {
            r1[j] = hv[j] - truncbf(hv[j]);
            r2[j] = r1[j] - truncbf(r1[j]);
        }
        bf1 = pk8(hv[0], hv[1], hv[2], hv[3], hv[4], hv[5], hv[6], hv[7]);
        bf2 = pk8(r1[0], r1[1], r1[2], r1[3], r1[4], r1[5], r1[6], r1[7]);
        bf3 = pk8(r2[0], r2[1], r2[2], r2[3], r2[4], r2[5], r2[6], r2[7]);

        xcur = xnx;
        xnx  = xf;
    }

    // ---- stash h (rows < 30) for classifier ----
    #pragma unroll
    for (int i = 0; i < 8; ++i) {
        const int row = 8 * q + i;
        if (row < NH) hf[m * 32 + row] = hv[i];
    }
    __syncthreads();

    // ---- classifier: 160 outputs (16 batches x 10 classes) ----
    #pragma unroll
    for (int it = 0; it < 3; ++it) {
        const int k = l + 64 * it;
        if (k < BPW * NC) {
            const int b = k / NC;
            const int c = k % NC;
            float acc = b_lin[c];
            #pragma unroll
            for (int i = 0; i < NH; ++i) {
                acc = fmaf(W_lin[c * NH + i], hf[b * 32 + i], acc);
            }
            out[((size_t)blk * BPW + b) * NC + c] = acc;
        }
    }
}

extern "C" void kernel_launch(void* const* d_in, const int* in_sizes, int n_in,
                              void* d_out, int out_size, void* d_ws, size_t ws_size,
                              hipStream_t stream) {
    const float* inp   = (const float*)d_in[0];
    const float* W_ih  = (const float*)d_in[1];
    const float* W_hh  = (const float*)d_in[2];
    const float* b_mod = (const float*)d_in[3];
    const float* W_lin = (const float*)d_in[4];
    const float* b_lin = (const float*)d_in[5];
    float* out = (float*)d_out;

    dim3 grid(NBATCH / BPW);   // 512 blocks
    dim3 block(64);            // one wave
    rnn_modrelu_mfma2<<<grid, block, 0, stream>>>(inp, W_ih, W_hh, b_mod,
                                                  W_lin, b_lin, out);
}

// Round 8
// 266.253 us; speedup vs baseline: 1.1455x; 1.1455x over previous
//
#include <hip/hip_runtime.h>

// expRNN/modReLU recurrence, B=8192, T=784, I=1, H=30, C=10.
//
// Round 8: 2-wave row-split of the split-precision bf16 MFMA step.
// R7 lesson: at 1 wave/SIMD with 512 waves, half the SIMDs idle and the
// serial chain (MFMA ~30cyc dep latency -> modrelu -> split -> pack) is
// fully exposed (765 cyc/iter vs ~220 issue). Fix: split each step's M
// dimension across 2 waves -> 1024 waves (all SIMDs), 6 MFMAs/wave as two
// 3-deep chains, epilogue on 4 values instead of 8.
//   - Wave g's A-frag at position m holds W row 8*(m>>2)+(m&3)+4g
//     (verified interleave); its C gives rows 8q+4g+i of batch m.
//   - Exchange: lane packs its 4 rows into 2 bf16-pair dwords per split
//     term and writes them into a shared per-lane fragment slot
//     ex[buf][term][q][m][4]; wave g owns dwords 2g,2g+1. After one
//     barrier both waves ds_read_b128 the COMPLETE next B fragment
//     (pairs never straddle halves). Double-buffered -> 1 barrier/iter.
//   - Numerics bit-identical to R6/R7 (same 6-term split products, x as
//     f32 acc-init): expect absmax == 3.17e29 (threshold/6.2).

#define T_STEPS 784
#define NBATCH  8192
#define NH      30
#define NC      10
#define BPW     16    // batches per block (= MFMA N)
#define XPAD    788   // padded x row; bank spread 20m mod 32 -> 2-way max

typedef short bf16x8 __attribute__((ext_vector_type(8)));
typedef float f32x4  __attribute__((ext_vector_type(4)));
typedef unsigned int u32x4 __attribute__((ext_vector_type(4)));
typedef unsigned int u32x2 __attribute__((ext_vector_type(2)));

#define MFMA(acc, a, b) \
    acc = __builtin_amdgcn_mfma_f32_16x16x32_bf16(a, b, acc, 0, 0, 0)

static __device__ __forceinline__ float truncbf(float x) {
    return __int_as_float(__float_as_int(x) & 0xFFFF0000);
}
// dword = bf16(lo) | bf16(hi)<<16 (hi16 bit-slices via byte perm)
static __device__ __forceinline__ unsigned pk2(float lo, float hi) {
    return __builtin_amdgcn_perm(__float_as_uint(hi), __float_as_uint(lo),
                                 0x07060302u);
}
static __device__ __forceinline__ bf16x8 pk8(const float* v) {
    u32x4 u = { pk2(v[0], v[1]), pk2(v[2], v[3]),
                pk2(v[4], v[5]), pk2(v[6], v[7]) };
    return __builtin_bit_cast(bf16x8, u);
}
static __device__ __forceinline__ float modrelu(float z, float b) {
    return copysignf(fmaxf(fabsf(z) + b, 0.0f), z);
}

__global__ __launch_bounds__(128, 1)
void rnn_rowsplit(const float* __restrict__ inp,    // [B, T, 1]
                  const float* __restrict__ W_ih,   // [H, 1]
                  const float* __restrict__ W_hh,   // [H, H]
                  const float* __restrict__ b_mod,  // [H]
                  const float* __restrict__ W_lin,  // [C, H]
                  const float* __restrict__ b_lin,  // [C]
                  float* __restrict__ out)          // [B, C]
{
    __shared__ __align__(16) float xl[BPW * XPAD];            // 50.4 KB
    __shared__ __align__(16) unsigned ex[2][3][4][16][4];     // 6 KB
    __shared__ __align__(16) float hf[BPW * 36];              // 2.3 KB

    const int tid = threadIdx.x;
    const int g   = tid >> 6;    // wave id: row-group
    const int l   = tid & 63;
    const int m   = l & 15;      // batch column
    const int q   = l >> 4;      // quad: B-frag k-range 8q..8q+7
    const int blk = blockIdx.x;

    // ---- stage x: 16 batches x 784 floats, coalesced, padded rows ----
    {
        const float4* src = (const float4*)(inp + (size_t)blk * (BPW * T_STEPS));
        #pragma unroll
        for (int k = 0; k < 25; ++k) {
            int v = tid + 128 * k;              // < 3136 float4
            if (v < (BPW * T_STEPS) / 4) {
                int b   = v / 196;
                int rem = v - b * 196;
                *(float4*)(xl + b * XPAD + 4 * rem) = src[v];
            }
        }
    }

    // ---- A fragments (this wave's row-group), 3 exact split terms ----
    bf16x8 a1, a2, a3;
    {
        const int row = 8 * (m >> 2) + (m & 3) + 4 * g;  // W row at A-pos m
        float wv[8], r1v[8], r2v[8];
        #pragma unroll
        for (int j = 0; j < 8; ++j) {
            const int col = q * 8 + j;
            float v = (row < NH && col < NH) ? W_hh[row * NH + col] : 0.0f;
            wv[j]  = v;
            r1v[j] = v - truncbf(v);
            r2v[j] = r1v[j] - truncbf(r1v[j]);
        }
        a1 = pk8(wv); a2 = pk8(r1v); a3 = pk8(r2v);
    }

    // own C rows: 8q + 4g + i
    float bm[4], wih[4];
    #pragma unroll
    for (int i = 0; i < 4; ++i) {
        const int row = 8 * q + 4 * g + i;
        bm[i]  = (row < NH) ? b_mod[row] : 0.0f;
        wih[i] = (row < NH) ? W_ih[row]  : 0.0f;
    }

    __syncthreads();

    const float* xb = xl + m * XPAD;
    float xcur = xb[0];
    float xnx  = xb[1];

    bf16x8 bf1 = {}, bf2 = {}, bf3 = {};     // h_0 = 0
    float hv[4] = {0.0f, 0.0f, 0.0f, 0.0f};

    // exchange slots (dword units); term stride = 256 dwords
    unsigned* const wr0 = &ex[0][0][q][m][2 * g];
    unsigned* const wr1 = &ex[1][0][q][m][2 * g];
    const unsigned* const rd0 = &ex[0][0][q][m][0];
    const unsigned* const rd1 = &ex[1][0][q][m][0];

    #pragma unroll 2
    for (int t = 0; t < T_STEPS; ++t) {
        int tf = t + 2; if (tf >= T_STEPS) tf = T_STEPS - 1;
        const float xf = xb[tf];             // prefetch x_{t+2}

        // two independent 3-deep MFMA chains; ca carries the f32 x-term
        f32x4 ca, cb;
        #pragma unroll
        for (int i = 0; i < 4; ++i) ca[i] = wih[i] * xcur;
        cb = (f32x4){0.0f, 0.0f, 0.0f, 0.0f};

        MFMA(ca, a1, bf1);   MFMA(cb, a2, bf1);   // w1h1 | w2h1
        MFMA(ca, a3, bf1);   MFMA(cb, a1, bf2);   // w3h1 | w1h2
        MFMA(ca, a2, bf2);   MFMA(cb, a1, bf3);   // w2h2 | w1h3

        // modReLU on own 4 rows (pad rows: w,b,wih==0 -> stay 0)
        #pragma unroll
        for (int i = 0; i < 4; ++i) hv[i] = modrelu(ca[i] + cb[i], bm[i]);

        // exact 3-term split of own rows
        float r1[4], r2[4];
        #pragma unroll
        for (int i = 0; i < 4; ++i) {
            r1[i] = hv[i] - truncbf(hv[i]);
            r2[i] = r1[i] - truncbf(r1[i]);
        }

        // pack own bf16-pair dwords and publish (pairs stay within half)
        unsigned* w = (t & 1) ? wr1 : wr0;
        *(u32x2*)(w +   0) = (u32x2){ pk2(hv[0], hv[1]), pk2(hv[2], hv[3]) };
        *(u32x2*)(w + 256) = (u32x2){ pk2(r1[0], r1[1]), pk2(r1[2], r1[3]) };
        *(u32x2*)(w + 512) = (u32x2){ pk2(r2[0], r2[1]), pk2(r2[2], r2[3]) };

        __syncthreads();   // lgkm drain publishes writes; dbuf -> 1 barrier

        // read the COMPLETE next B fragments (own + sibling halves)
        const unsigned* r = (t & 1) ? rd1 : rd0;
        bf1 = __builtin_bit_cast(bf16x8, *(const u32x4*)(r + 0));
        bf2 = __builtin_bit_cast(bf16x8, *(const u32x4*)(r + 256));
        bf3 = __builtin_bit_cast(bf16x8, *(const u32x4*)(r + 512));

        xcur = xnx; xnx = xf;
    }

    // ---- stash own f32 rows of h_T for the classifier ----
    *(float4*)(hf + m * 36 + 8 * q + 4 * g) =
        make_float4(hv[0], hv[1], hv[2], hv[3]);
    __syncthreads();

    // ---- classifier: 160 outputs (16 batches x 10 classes) ----
    #pragma unroll
    for (int it = 0; it < 2; ++it) {
        const int k = tid + 128 * it;
        if (k < BPW * NC) {
            const int b = k / NC;
            const int c = k % NC;
            float acc = b_lin[c];
            #pragma unroll
            for (int i = 0; i < NH; ++i) {
                acc = fmaf(W_lin[c * NH + i], hf[b * 36 + i], acc);
            }
            out[((size_t)blk * BPW + b) * NC + c] = acc;
        }
    }
}

extern "C" void kernel_launch(void* const* d_in, const int* in_sizes, int n_in,
                              void* d_out, int out_size, void* d_ws, size_t ws_size,
                              hipStream_t stream) {
    const float* inp   = (const float*)d_in[0];
    const float* W_ih  = (const float*)d_in[1];
    const float* W_hh  = (const float*)d_in[2];
    const float* b_mod = (const float*)d_in[3];
    const float* W_lin = (const float*)d_in[4];
    const float* b_lin = (const float*)d_in[5];
    float* out = (float*)d_out;

    dim3 grid(NBATCH / BPW);   // 512 blocks
    dim3 block(128);           // two waves: row-groups 0 and 1
    rnn_rowsplit<<<grid, block, 0, stream>>>(inp, W_ih, W_hh, b_mod,
                                             W_lin, b_lin, out);
}